// Round 3
// baseline (3049.699 us; speedup 1.0000x reference)
//
#include <hip/hip_runtime.h>

#define BB 64
#define SS 1024
#define II 128
#define HH 256
#define OO 128
#define NB 16   // batches per recurrent block

typedef __fp16 h2_t __attribute__((ext_vector_type(2)));
typedef _Float16 f16x8 __attribute__((ext_vector_type(8)));
typedef float f32x4 __attribute__((ext_vector_type(4)));

__device__ __forceinline__ unsigned packh(float a, float b) {
    union { h2_t h; unsigned u; } cv;
    cv.h = __builtin_amdgcn_cvt_pkrtz(a, b);   // v_cvt_pkrtz_f16_f32
    return cv.u;
}

// fast transcendentals: error ~1e-6, below the f16-weight noise floor.
__device__ __forceinline__ float fsigmoid(float x) {
    float e = __builtin_amdgcn_exp2f(-1.4426950408889634f * x);
    return __builtin_amdgcn_rcpf(1.0f + e);
}
__device__ __forceinline__ float ftanh(float x) {
    float e = __builtin_amdgcn_exp2f(2.8853900817779268f * x);   // e^(2x)
    return 1.0f - 2.0f * __builtin_amdgcn_rcpf(1.0f + e);
}

// barrier without vmcnt drain: per-step global store / prefetch stay in flight.
__device__ __forceinline__ void bar_lds() {
    asm volatile("s_waitcnt lgkmcnt(0)\n\ts_barrier" ::: "memory");
}

// ---------------------------------------------------------------------------
// Kernel A: inp[b,t,h] = x[b,t,:] @ W_in[h,:] + (b_in[h] + b_rec[h])
// b_rec folded here so the recurrent kernel's rec-acc needs no bias.
// ---------------------------------------------------------------------------
__global__ __launch_bounds__(256)
void ltc_inproj(const float* __restrict__ x, const float* __restrict__ W_in,
                const float* __restrict__ b_in, const float* __restrict__ b_rec,
                float* __restrict__ inp)
{
    __shared__ float smem[64 * 130];
    const int t = threadIdx.x;
    const int l = t & 63, w = t >> 6;
    const int r0 = blockIdx.x * 64;

    float2* xs2 = (float2*)smem;                // [64][65] float2
    for (int idx = t; idx < 64 * 64; idx += 256) {
        int row = idx >> 6, c2 = idx & 63;
        xs2[row * 65 + c2] = ((const float2*)x)[(size_t)(r0 + row) * 64 + c2];
    }
    __syncthreads();
    float xr[128];
#pragma unroll
    for (int i = 0; i < 64; ++i) {
        float2 v = xs2[l * 65 + i];
        xr[2 * i] = v.x; xr[2 * i + 1] = v.y;
    }
    __syncthreads();

    for (int ph = 0; ph < 2; ++ph) {
        for (int i = 0; i < 32; ++i) {
            const int hh = 128 * ph + 32 * w + i;
            const float4* wr = (const float4*)(W_in + (size_t)hh * II);
            float a0 = b_in[hh] + b_rec[hh], a1 = 0.f, a2 = 0.f, a3 = 0.f;
#pragma unroll
            for (int j = 0; j < 32; ++j) {
                float4 wv = wr[j];
                a0 = fmaf(wv.x, xr[4 * j + 0], a0);
                a1 = fmaf(wv.y, xr[4 * j + 1], a1);
                a2 = fmaf(wv.z, xr[4 * j + 2], a2);
                a3 = fmaf(wv.w, xr[4 * j + 3], a3);
            }
            smem[l * 128 + ((32 * w + i + l) & 127)] = a0 + a1 + a2 + a3;
        }
        __syncthreads();
        for (int k = 0; k < 32; ++k) {
            int idx = k * 256 + t;
            int row = idx >> 7, c = idx & 127;
            inp[(size_t)(r0 + row) * HH + 128 * ph + c] = smem[row * 128 + ((c + row) & 127)];
        }
        __syncthreads();
    }
}

// ---------------------------------------------------------------------------
// Kernel B (NEW): MFMA batched recurrence. 4 blocks x 512 thr; block bg owns
// batches bg*16..bg*16+15. Per step: 3 matmuls [256x256]x[256x16] via
// mfma_f32_16x16x32_f16. Wave wv owns row-tiles m0=32*wv (rows m0..m0+31).
// Lane l: A-row / D-col role: batch = l&15, q = l>>4.
//   A-frag (W, f16, regs): elem j = W[m0+16*tt + (l&15)][kb*32 + q*8 + j]
//   B-frag (h, LDS hT):    elem j = h[kb*32 + q*8 + j][batch], read b128 from
//       hT[batch][kdw ^ swz] (XOR swizzle -> conflict-free at b128 floor)
//   D/C:  col = batch = l&15, row = m0+16*tt + 4*q + reg   (m89-verified)
// acc-init carries inp (rec) and biases (cg/eg) -> no bias adds in pointwise.
// h kept f32 in regs (static per-lane rows); f16 copy to hT for next matmul;
// states written as coalesced float4. One lgkm-barrier per step; hT and
// inp_s double-buffered.
// ---------------------------------------------------------------------------
__global__ __launch_bounds__(512)
void ltc_rec_mfma(const float* __restrict__ W_rec,
                  const float* __restrict__ W_cg,  const float* __restrict__ b_cg,
                  const float* __restrict__ W_eg,  const float* __restrict__ b_eg,
                  const float* __restrict__ tau,
                  float* __restrict__ st)          // [B,S,H]: inp staged in, states out
{
    const int bg = blockIdx.x, t = threadIdx.x;
    const int wv = t >> 6, l = t & 63;
    const int batch = l & 15, q = l >> 4;
    const int m0 = wv * 32;
    const int swz = (batch & 7) << 2;

    __shared__ __align__(16) unsigned hT[2][NB][128];    // packed f16 h, swizzled
    __shared__ __align__(16) float inp_s[2][NB][260];    // staged inp (pad +4)
    __shared__ __align__(16) float bC_s[HH];
    __shared__ __align__(16) float bE_s[HH];
    __shared__ __align__(16) float ti_s[HH];

    union F { unsigned u[4]; uint4 q4; f16x8 v; };
    F wR[2][8], wC[2][8], wE[2][8];

#pragma unroll
    for (int tt = 0; tt < 2; ++tt) {
        const int row = m0 + 16 * tt + batch;            // here (l&15) = A-row
#pragma unroll
        for (int kb = 0; kb < 8; ++kb) {
            const float* pR = W_rec + (size_t)row * HH + kb * 32 + q * 8;
            const float* pC = W_cg  + (size_t)row * HH + kb * 32 + q * 8;
            const float* pE = W_eg  + (size_t)row * HH + kb * 32 + q * 8;
            float4 a, b;
            a = ((const float4*)pR)[0]; b = ((const float4*)pR)[1];
            wR[tt][kb].u[0] = packh(a.x, a.y); wR[tt][kb].u[1] = packh(a.z, a.w);
            wR[tt][kb].u[2] = packh(b.x, b.y); wR[tt][kb].u[3] = packh(b.z, b.w);
            a = ((const float4*)pC)[0]; b = ((const float4*)pC)[1];
            wC[tt][kb].u[0] = packh(a.x, a.y); wC[tt][kb].u[1] = packh(a.z, a.w);
            wC[tt][kb].u[2] = packh(b.x, b.y); wC[tt][kb].u[3] = packh(b.z, b.w);
            a = ((const float4*)pE)[0]; b = ((const float4*)pE)[1];
            wE[tt][kb].u[0] = packh(a.x, a.y); wE[tt][kb].u[1] = packh(a.z, a.w);
            wE[tt][kb].u[2] = packh(b.x, b.y); wE[tt][kb].u[3] = packh(b.z, b.w);
        }
    }

    if (t < HH) {
        bC_s[t] = b_cg[t];
        bE_s[t] = b_eg[t];
        ti_s[t] = 1.0f / tau[t];
    }
    ((uint4*)&hT[0][0][0])[t] = make_uint4(0u, 0u, 0u, 0u);   // zero hT[0] (8KB)

    const int j0 = t, j1 = t + 512;                      // staging element ids
    const float* pf0p = st + (size_t)(bg * NB + (j0 >> 6)) * SS * HH + (j0 & 63) * 4;
    const float* pf1p = st + (size_t)(bg * NB + (j1 >> 6)) * SS * HH + (j1 & 63) * 4;
    {
        float4 v0 = *(const float4*)pf0p;                // s = 0
        float4 v1 = *(const float4*)pf1p;
        *(float4*)&inp_s[0][j0 >> 6][(j0 & 63) * 4] = v0;
        *(float4*)&inp_s[0][j1 >> 6][(j1 & 63) * 4] = v1;
    }
    __syncthreads();

    float h0[4] = {0.f, 0.f, 0.f, 0.f};                  // rows m0+4q+0..3
    float h1[4] = {0.f, 0.f, 0.f, 0.f};                  // rows m0+16+4q+0..3
    float* stB = st + (size_t)(bg * NB + batch) * SS * HH + m0 + 4 * q;

    for (int s = 0; s < SS; ++s) {
        const int cur = s & 1, nxt = cur ^ 1;

        float4 pf0, pf1;
        const bool dopf = (s + 1 < SS);
        if (dopf) {
            pf0 = *(const float4*)(pf0p + (size_t)(s + 1) * HH);
            pf1 = *(const float4*)(pf1p + (size_t)(s + 1) * HH);
        }

        // acc init: rec <- inp(+b_in+b_rec); cg <- b_cg; eg <- b_eg
        f32x4 aR0 = *(const f32x4*)&inp_s[cur][batch][m0 + 4 * q];
        f32x4 aR1 = *(const f32x4*)&inp_s[cur][batch][m0 + 16 + 4 * q];
        f32x4 aC0 = *(const f32x4*)&bC_s[m0 + 4 * q];
        f32x4 aC1 = *(const f32x4*)&bC_s[m0 + 16 + 4 * q];
        f32x4 aE0 = *(const f32x4*)&bE_s[m0 + 4 * q];
        f32x4 aE1 = *(const f32x4*)&bE_s[m0 + 16 + 4 * q];

#pragma unroll
        for (int kb = 0; kb < 8; ++kb) {
            F bf;
            bf.q4 = *(const uint4*)&hT[cur][batch][(kb * 16 + q * 4) ^ swz];
            aR0 = __builtin_amdgcn_mfma_f32_16x16x32_f16(wR[0][kb].v, bf.v, aR0, 0, 0, 0);
            aC0 = __builtin_amdgcn_mfma_f32_16x16x32_f16(wC[0][kb].v, bf.v, aC0, 0, 0, 0);
            aE0 = __builtin_amdgcn_mfma_f32_16x16x32_f16(wE[0][kb].v, bf.v, aE0, 0, 0, 0);
            aR1 = __builtin_amdgcn_mfma_f32_16x16x32_f16(wR[1][kb].v, bf.v, aR1, 0, 0, 0);
            aC1 = __builtin_amdgcn_mfma_f32_16x16x32_f16(wC[1][kb].v, bf.v, aC1, 0, 0, 0);
            aE1 = __builtin_amdgcn_mfma_f32_16x16x32_f16(wE[1][kb].v, bf.v, aE1, 0, 0, 0);
        }

        f32x4 ti0 = *(const f32x4*)&ti_s[m0 + 4 * q];
        f32x4 ti1 = *(const f32x4*)&ti_s[m0 + 16 + 4 * q];

#pragma unroll
        for (int k = 0; k < 4; ++k) {
            float rl = fmaxf(aR0[k], 0.f);
            float cm = fsigmoid(aC0[k]);
            float em = ftanh(aE0[k]);
            float dh = (rl - h0[k]) * ti0[k] * cm + 0.1f * em;
            h0[k] = fmaf(0.1f, dh, h0[k]);
        }
#pragma unroll
        for (int k = 0; k < 4; ++k) {
            float rl = fmaxf(aR1[k], 0.f);
            float cm = fsigmoid(aC1[k]);
            float em = ftanh(aE1[k]);
            float dh = (rl - h1[k]) * ti1[k] * cm + 0.1f * em;
            h1[k] = fmaf(0.1f, dh, h1[k]);
        }

        {   // tile 0: pack f16 pair-dwords + coalesced f32 states
            unsigned p0 = packh(h0[0], h0[1]), p1 = packh(h0[2], h0[3]);
            int kdw = ((m0 + 4 * q) >> 1) ^ swz;
            *(uint2*)&hT[nxt][batch][kdw] = make_uint2(p0, p1);
            *(float4*)(stB + (size_t)s * HH) = make_float4(h0[0], h0[1], h0[2], h0[3]);
        }
        {   // tile 1
            unsigned p0 = packh(h1[0], h1[1]), p1 = packh(h1[2], h1[3]);
            int kdw = ((m0 + 16 + 4 * q) >> 1) ^ swz;
            *(uint2*)&hT[nxt][batch][kdw] = make_uint2(p0, p1);
            *(float4*)(stB + (size_t)s * HH + 16) = make_float4(h1[0], h1[1], h1[2], h1[3]);
        }

        if (dopf) {   // compiler inserts vmcnt wait for pf before these writes
            *(float4*)&inp_s[nxt][j0 >> 6][(j0 & 63) * 4] = pf0;
            *(float4*)&inp_s[nxt][j1 >> 6][(j1 & 63) * 4] = pf1;
        }
        bar_lds();
    }
}

// ---------------------------------------------------------------------------
// Kernel C: outputs[row,o] = b_out[o] + states[row,:] @ W_out[o,:]
// ---------------------------------------------------------------------------
__global__ __launch_bounds__(256)
void ltc_out(const float* __restrict__ states, const float* __restrict__ W_out,
             const float* __restrict__ b_out, float* __restrict__ outputs)
{
    __shared__ float smem[64 * 130];
    const int t = threadIdx.x;
    const int l = t & 63, w = t >> 6;
    const int r0 = blockIdx.x * 64;

    float osacc[32];
#pragma unroll
    for (int i = 0; i < 32; ++i) osacc[i] = b_out[32 * w + i];

    float2* xs2 = (float2*)smem;                // [64][65] float2
    for (int ph = 0; ph < 2; ++ph) {
        for (int idx = t; idx < 64 * 64; idx += 256) {
            int row = idx >> 6, c2 = idx & 63;
            xs2[row * 65 + c2] = ((const float2*)states)[(size_t)(r0 + row) * 128 + ph * 64 + c2];
        }
        __syncthreads();
        float xr[128];
#pragma unroll
        for (int i = 0; i < 64; ++i) {
            float2 v = xs2[l * 65 + i];
            xr[2 * i] = v.x; xr[2 * i + 1] = v.y;
        }
        __syncthreads();

        for (int i = 0; i < 32; ++i) {
            const int oo = 32 * w + i;
            const float4* wr = (const float4*)(W_out + (size_t)oo * HH + ph * 128);
            float a0 = 0.f, a1 = 0.f, a2 = 0.f, a3 = 0.f;
#pragma unroll
            for (int j = 0; j < 32; ++j) {
                float4 wv = wr[j];
                a0 = fmaf(wv.x, xr[4 * j + 0], a0);
                a1 = fmaf(wv.y, xr[4 * j + 1], a1);
                a2 = fmaf(wv.z, xr[4 * j + 2], a2);
                a3 = fmaf(wv.w, xr[4 * j + 3], a3);
            }
            osacc[i] += (a0 + a1) + (a2 + a3);
        }
    }

    __syncthreads();
#pragma unroll
    for (int i = 0; i < 32; ++i)
        smem[l * 128 + ((32 * w + i + l) & 127)] = osacc[i];
    __syncthreads();
    for (int k = 0; k < 32; ++k) {
        int idx = k * 256 + t;
        int row = idx >> 7, c = idx & 127;
        outputs[(size_t)(r0 + row) * OO + c] = smem[row * 128 + ((c + row) & 127)];
    }
}

extern "C" void kernel_launch(void* const* d_in, const int* in_sizes, int n_in,
                              void* d_out, int out_size, void* d_ws, size_t ws_size,
                              hipStream_t stream) {
    const float* x      = (const float*)d_in[0];
    const float* W_in   = (const float*)d_in[1];
    const float* b_in   = (const float*)d_in[2];
    const float* W_rec  = (const float*)d_in[3];
    const float* b_rec  = (const float*)d_in[4];
    const float* W_out  = (const float*)d_in[5];
    const float* b_out  = (const float*)d_in[6];
    const float* W_cg   = (const float*)d_in[7];
    const float* b_cg   = (const float*)d_in[8];
    const float* W_eg   = (const float*)d_in[9];
    const float* b_eg   = (const float*)d_in[10];
    const float* tau    = (const float*)d_in[11];

    float* outputs = (float*)d_out;                       // [B,S,O]
    float* states  = outputs + (size_t)BB * SS * OO;      // [B,S,H] (inp staging -> states)

    hipLaunchKernelGGL(ltc_inproj, dim3(BB * SS / 64), dim3(256), 0, stream,
                       x, W_in, b_in, b_rec, states);
    hipLaunchKernelGGL(ltc_rec_mfma, dim3(BB / NB), dim3(512), 0, stream,
                       W_rec, W_cg, b_cg, W_eg, b_eg, tau, states);
    hipLaunchKernelGGL(ltc_out, dim3(BB * SS / 64), dim3(256), 0, stream,
                       states, W_out, b_out, outputs);
}

// Round 4
// 2317.230 us; speedup vs baseline: 1.3161x; 1.3161x over previous
//
#include <hip/hip_runtime.h>

#define BB 64
#define SS 1024
#define II 128
#define HH 256
#define OO 128

#if __has_builtin(__builtin_amdgcn_fdot2)
#define HAVE_DOT2 1
#endif

typedef __fp16 h2_t __attribute__((ext_vector_type(2)));

__device__ __forceinline__ float blo(unsigned u) { return __uint_as_float(u << 16); }
__device__ __forceinline__ float bhi(unsigned u) { return __uint_as_float(u & 0xffff0000u); }

__device__ __forceinline__ unsigned pack_bf2(float a, float b) {
    unsigned ua = __float_as_uint(a);
    unsigned ub = __float_as_uint(b);
    ua = (ua + 0x7fffu + ((ua >> 16) & 1u)) >> 16;
    ub = (ub + 0x7fffu + ((ub >> 16) & 1u)) & 0xffff0000u;
    return ua | ub;
}

__device__ __forceinline__ unsigned packh(float a, float b) {
#ifdef HAVE_DOT2
    union { h2_t h; unsigned u; } cv;
    cv.h = __builtin_amdgcn_cvt_pkrtz(a, b);   // v_cvt_pkrtz_f16_f32
    return cv.u;
#else
    return pack_bf2(a, b);
#endif
}

__device__ __forceinline__ float dot2acc(unsigned w, unsigned h, float acc) {
#ifdef HAVE_DOT2
    union { unsigned u; h2_t h; } cw, ch;
    cw.u = w; ch.u = h;
    return __builtin_amdgcn_fdot2(cw.h, ch.h, acc, false);
#else
    return fmaf(blo(w), blo(h), fmaf(bhi(w), bhi(h), acc));
#endif
}

// fast transcendentals: error ~1e-6, below the f16-weight noise floor.
__device__ __forceinline__ float fsigmoid(float x) {
    float e = __builtin_amdgcn_exp2f(-1.4426950408889634f * x);
    return __builtin_amdgcn_rcpf(1.0f + e);
}
__device__ __forceinline__ float ftanh(float x) {
    float e = __builtin_amdgcn_exp2f(2.8853900817779268f * x);   // e^(2x)
    return 1.0f - 2.0f * __builtin_amdgcn_rcpf(1.0f + e);
}

// barrier without vmcnt drain: per-step global store / prefetch stay in flight.
__device__ __forceinline__ void bar_lds() {
    asm volatile("s_waitcnt lgkmcnt(0)\n\ts_barrier" ::: "memory");
}

// ---------------------------------------------------------------------------
// Kernel A: inp[b,t,h] = x[b,t,:] @ W_in[h,:] + (b_in[h] + b_rec[h])
// b_rec folded here so the recurrent kernel's rec-acc needs no bias.
// ---------------------------------------------------------------------------
__global__ __launch_bounds__(256)
void ltc_inproj(const float* __restrict__ x, const float* __restrict__ W_in,
                const float* __restrict__ b_in, const float* __restrict__ b_rec,
                float* __restrict__ inp)
{
    __shared__ float smem[64 * 130];
    const int t = threadIdx.x;
    const int l = t & 63, w = t >> 6;
    const int r0 = blockIdx.x * 64;

    float2* xs2 = (float2*)smem;                // [64][65] float2
    for (int idx = t; idx < 64 * 64; idx += 256) {
        int row = idx >> 6, c2 = idx & 63;
        xs2[row * 65 + c2] = ((const float2*)x)[(size_t)(r0 + row) * 64 + c2];
    }
    __syncthreads();
    float xr[128];
#pragma unroll
    for (int i = 0; i < 64; ++i) {
        float2 v = xs2[l * 65 + i];
        xr[2 * i] = v.x; xr[2 * i + 1] = v.y;
    }
    __syncthreads();

    for (int ph = 0; ph < 2; ++ph) {
        for (int i = 0; i < 32; ++i) {
            const int hh = 128 * ph + 32 * w + i;
            const float4* wr = (const float4*)(W_in + (size_t)hh * II);
            float a0 = b_in[hh] + b_rec[hh], a1 = 0.f, a2 = 0.f, a3 = 0.f;
#pragma unroll
            for (int j = 0; j < 32; ++j) {
                float4 wv = wr[j];
                a0 = fmaf(wv.x, xr[4 * j + 0], a0);
                a1 = fmaf(wv.y, xr[4 * j + 1], a1);
                a2 = fmaf(wv.z, xr[4 * j + 2], a2);
                a3 = fmaf(wv.w, xr[4 * j + 3], a3);
            }
            smem[l * 128 + ((32 * w + i + l) & 127)] = a0 + a1 + a2 + a3;
        }
        __syncthreads();
        for (int k = 0; k < 32; ++k) {
            int idx = k * 256 + t;
            int row = idx >> 7, c = idx & 127;
            inp[(size_t)(r0 + row) * HH + 128 * ph + c] = smem[row * 128 + ((c + row) & 127)];
        }
        __syncthreads();
    }
}

// ---------------------------------------------------------------------------
// Kernel B: persistent recurrence, R=2 row-pair structure.
// 64 blocks x 512 thr (8 waves, 2/SIMD). Thread t -> (p = t>>2, qt = t&3):
// owns rows {2p, 2p+1} x k-quarter [qt*64, qt*64+64) for all 3 gates.
//   - h-slice per thread = 32 packed dwords = 8 ds_read_b128 (HALF of round-2:
//     2 rows share one h load -> LDS pipe ~64 wave-insts/CU/step vs 128)
//   - weights: 6 x 32 packed dwords = 192 (same as round-2, fits reg budget)
//   - quarter-partials reduced via __shfl_xor(1,2) = DPP quad_perm (VALU pipe)
//   - pointwise redundant on the 4 quad lanes (lockstep)
//   - hT: 512B per buffer, double-buffered, uint4-XOR swizzle:
//       logical uint4 u stored at (u&~7) | ((u&7) ^ (u>>3))
//     read: 4 distinct bank-groups (broadcast within 16-lane qt groups);
//     write: 16 distinct banks. Conflict-free both sides.
//   - inp: no LDS staging; per-pair float2 loads (4-lane broadcast), prefetch 1.
//   - ONE lgkm-only barrier per step (global ops never drained in-loop).
// ---------------------------------------------------------------------------
__global__ __launch_bounds__(512)
void ltc_recurrent(const float* __restrict__ W_rec,
                   const float* __restrict__ W_cg,  const float* __restrict__ b_cg,
                   const float* __restrict__ W_eg,  const float* __restrict__ b_eg,
                   const float* __restrict__ tau,
                   float* __restrict__ st)          // [B,S,H]: inp staged in, states out
{
    const int b = blockIdx.x, t = threadIdx.x;
    const int p = t >> 2, qt = t & 3;               // pair 0..127, k-quarter 0..3
    const int r0 = 2 * p, r1 = 2 * p + 1;

    __shared__ __align__(16) uint4 hT[2][32];       // 2 x 512B packed-f16 h, swizzled

    unsigned wR0[32], wR1[32], wC0[32], wC1[32], wE0[32], wE1[32];
#define LOADW(dst, base) { const float4* p4_ = (const float4*)(base); \
    _Pragma("unroll") for (int j = 0; j < 16; ++j) { float4 v_ = p4_[j]; \
        dst[2 * j] = packh(v_.x, v_.y); dst[2 * j + 1] = packh(v_.z, v_.w); } }
    LOADW(wR0, W_rec + (size_t)r0 * HH + qt * 64)
    LOADW(wR1, W_rec + (size_t)r1 * HH + qt * 64)
    LOADW(wC0, W_cg  + (size_t)r0 * HH + qt * 64)
    LOADW(wC1, W_cg  + (size_t)r1 * HH + qt * 64)
    LOADW(wE0, W_eg  + (size_t)r0 * HH + qt * 64)
    LOADW(wE1, W_eg  + (size_t)r1 * HH + qt * 64)
#undef LOADW

    const float ti0 = 1.0f / tau[r0], ti1 = 1.0f / tau[r1];
    const float bC0 = b_cg[r0], bC1 = b_cg[r1];
    const float bE0 = b_eg[r0], bE1 = b_eg[r1];

    float* stb = st + (size_t)b * SS * HH;
    float h0 = 0.f, h1 = 0.f;                       // rows 2p, 2p+1
    float2 inpC = ((const float2*)stb)[p];          // inp(0, {2p,2p+1})

    if (t < 32) hT[0][t] = make_uint4(0u, 0u, 0u, 0u);
    __syncthreads();

    for (int s = 0; s < SS; ++s) {
        const int cur = s & 1, nxt = cur ^ 1;

        float2 pf;
        const bool dopf = (s + 1 < SS);
        if (dopf) pf = ((const float2*)(stb + (size_t)(s + 1) * HH))[p];

        // this thread's 8 swizzled uint4: logical u = qt*8+c at storage qt*8+(c^qt)
        const uint4* hb = hT[cur];
        uint4 hq[8];
#pragma unroll
        for (int c = 0; c < 8; ++c) hq[c] = hb[qt * 8 + (c ^ qt)];

        float aR0 = 0.f, aR1 = 0.f, aC0 = 0.f, aC1 = 0.f, aE0 = 0.f, aE1 = 0.f;
#pragma unroll
        for (int c = 0; c < 8; ++c) {
#define DOTD(J, HW) \
            aR0 = dot2acc(wR0[4 * c + J], HW, aR0); \
            aR1 = dot2acc(wR1[4 * c + J], HW, aR1); \
            aC0 = dot2acc(wC0[4 * c + J], HW, aC0); \
            aC1 = dot2acc(wC1[4 * c + J], HW, aC1); \
            aE0 = dot2acc(wE0[4 * c + J], HW, aE0); \
            aE1 = dot2acc(wE1[4 * c + J], HW, aE1);
            DOTD(0, hq[c].x)
            DOTD(1, hq[c].y)
            DOTD(2, hq[c].z)
            DOTD(3, hq[c].w)
#undef DOTD
        }
        // reduce across the 4 k-quarters (quad lanes; DPP, stays on VALU pipe)
        aR0 += __shfl_xor(aR0, 1); aR0 += __shfl_xor(aR0, 2);
        aR1 += __shfl_xor(aR1, 1); aR1 += __shfl_xor(aR1, 2);
        aC0 += __shfl_xor(aC0, 1); aC0 += __shfl_xor(aC0, 2);
        aC1 += __shfl_xor(aC1, 1); aC1 += __shfl_xor(aC1, 2);
        aE0 += __shfl_xor(aE0, 1); aE0 += __shfl_xor(aE0, 2);
        aE1 += __shfl_xor(aE1, 1); aE1 += __shfl_xor(aE1, 2);

        // pointwise for rows 2p, 2p+1 (all 4 quad lanes compute identically)
        float cm0 = fsigmoid(aC0 + bC0), em0 = ftanh(aE0 + bE0);
        float cm1 = fsigmoid(aC1 + bC1), em1 = ftanh(aE1 + bE1);
        float p0 = inpC.x + aR0, p1 = inpC.y + aR1;
        float rl0 = fmaxf(p0, 0.f), rl1 = fmaxf(p1, 0.f);
        float dh0 = (rl0 - h0) * ti0 * cm0 + 0.1f * em0;
        float dh1 = (rl1 - h1) * ti1 * cm1 + 0.1f * em1;
        h0 = fmaf(0.1f, dh0, h0);
        h1 = fmaf(0.1f, dh1, h1);

        if (qt == 0) {
            unsigned pk = packh(h0, h1);            // logical dword d = p
            int u = p >> 2, c = u & 7, g = u >> 3;
            ((unsigned*)hT[nxt])[(g * 8 + (c ^ g)) * 4 + (p & 3)] = pk;
            float2 hv; hv.x = h0; hv.y = h1;
            ((float2*)(stb + (size_t)s * HH))[p] = hv;
        }
        if (dopf) inpC = pf;
        bar_lds();                                  // hT[nxt] visible for next step
    }
}

// ---------------------------------------------------------------------------
// Kernel C: outputs[row,o] = b_out[o] + states[row,:] @ W_out[o,:]
// ---------------------------------------------------------------------------
__global__ __launch_bounds__(256)
void ltc_out(const float* __restrict__ states, const float* __restrict__ W_out,
             const float* __restrict__ b_out, float* __restrict__ outputs)
{
    __shared__ float smem[64 * 130];
    const int t = threadIdx.x;
    const int l = t & 63, w = t >> 6;
    const int r0 = blockIdx.x * 64;

    float osacc[32];
#pragma unroll
    for (int i = 0; i < 32; ++i) osacc[i] = b_out[32 * w + i];

    float2* xs2 = (float2*)smem;                // [64][65] float2
    for (int ph = 0; ph < 2; ++ph) {
        for (int idx = t; idx < 64 * 64; idx += 256) {
            int row = idx >> 6, c2 = idx & 63;
            xs2[row * 65 + c2] = ((const float2*)states)[(size_t)(r0 + row) * 128 + ph * 64 + c2];
        }
        __syncthreads();
        float xr[128];
#pragma unroll
        for (int i = 0; i < 64; ++i) {
            float2 v = xs2[l * 65 + i];
            xr[2 * i] = v.x; xr[2 * i + 1] = v.y;
        }
        __syncthreads();

        for (int i = 0; i < 32; ++i) {
            const int oo = 32 * w + i;
            const float4* wr = (const float4*)(W_out + (size_t)oo * HH + ph * 128);
            float a0 = 0.f, a1 = 0.f, a2 = 0.f, a3 = 0.f;
#pragma unroll
            for (int j = 0; j < 32; ++j) {
                float4 wv = wr[j];
                a0 = fmaf(wv.x, xr[4 * j + 0], a0);
                a1 = fmaf(wv.y, xr[4 * j + 1], a1);
                a2 = fmaf(wv.z, xr[4 * j + 2], a2);
                a3 = fmaf(wv.w, xr[4 * j + 3], a3);
            }
            osacc[i] += (a0 + a1) + (a2 + a3);
        }
    }

    __syncthreads();
#pragma unroll
    for (int i = 0; i < 32; ++i)
        smem[l * 128 + ((32 * w + i + l) & 127)] = osacc[i];
    __syncthreads();
    for (int k = 0; k < 32; ++k) {
        int idx = k * 256 + t;
        int row = idx >> 7, c = idx & 127;
        outputs[(size_t)(r0 + row) * OO + c] = smem[row * 128 + ((c + row) & 127)];
    }
}

extern "C" void kernel_launch(void* const* d_in, const int* in_sizes, int n_in,
                              void* d_out, int out_size, void* d_ws, size_t ws_size,
                              hipStream_t stream) {
    const float* x      = (const float*)d_in[0];
    const float* W_in   = (const float*)d_in[1];
    const float* b_in   = (const float*)d_in[2];
    const float* W_rec  = (const float*)d_in[3];
    const float* b_rec  = (const float*)d_in[4];
    const float* W_out  = (const float*)d_in[5];
    const float* b_out  = (const float*)d_in[6];
    const float* W_cg   = (const float*)d_in[7];
    const float* b_cg   = (const float*)d_in[8];
    const float* W_eg   = (const float*)d_in[9];
    const float* b_eg   = (const float*)d_in[10];
    const float* tau    = (const float*)d_in[11];

    float* outputs = (float*)d_out;                       // [B,S,O]
    float* states  = outputs + (size_t)BB * SS * OO;      // [B,S,H] (inp staging -> states)

    hipLaunchKernelGGL(ltc_inproj, dim3(BB * SS / 64), dim3(256), 0, stream,
                       x, W_in, b_in, b_rec, states);
    hipLaunchKernelGGL(ltc_recurrent, dim3(BB), dim3(512), 0, stream,
                       W_rec, W_cg, b_cg, W_eg, b_eg, tau, states);
    hipLaunchKernelGGL(ltc_out, dim3(BB * SS / 64), dim3(256), 0, stream,
                       states, W_out, b_out, outputs);
}